// Round 10
// baseline (72815.985 us; speedup 1.0000x reference)
//
#include <hip/hip_runtime.h>

#define T_STEPS 8192
#define HID 1024
#define G4 4096
#define NBLK 128    // blocks per layer; grid = 256
#define NTHR 512    // 8 waves
#define NSLOT 8     // rotation depth

typedef unsigned int uint32;
typedef unsigned long long ull;

// Global comm (memset 0xFF each launch): tagged fp32 h values, packed as ull
// pairs (8B-aligned for the paired publish; detect casts down to uint32).
// Slot s = t & 7; tag = (t>>3) & 15 in the 4 low mantissa bits of each fp32.
struct Comm {
    ull hA[NSLOT][HID / 2];   // layer-0 h
    ull hB[NSLOT][HID / 2];   // layer-1 h
};

#define LD_AG  __HIP_MEMORY_SCOPE_AGENT
#define LD_WG  __HIP_MEMORY_SCOPE_WORKGROUP

__device__ inline float sigm(float x) { return 1.0f / (1.0f + __expf(-x)); }
__device__ inline float tanh_f(float x) {
    x = fminf(fmaxf(x, -15.f), 15.f);
    float e = __expf(-2.0f * x);
    return (1.0f - e) / (1.0f + e);
}
__device__ inline uint32 tagf(float f, uint32 tg) {
    union { float f; uint32 u; } a; a.f = f;
    return (a.u & ~15u) | tg;
}

// out[m][perm(n)] = A[m][:] . W[n][:] + bi[n] + bh[n]
// perm: j = n&1023, gate = n>>10; idx = (j>>3)*32 + (j&7)*4 + gate
__global__ __launch_bounds__(256)
void gemm_xg(const float* __restrict__ A, const float* __restrict__ W,
             const float* __restrict__ bi, const float* __restrict__ bh,
             float* __restrict__ out)
{
    __shared__ float As[16][65];
    __shared__ float Bs[16][65];
    const int tid = threadIdx.x;
    const int m0 = blockIdx.y * 64, n0 = blockIdx.x * 64;
    const int tm = tid & 15, tn = tid >> 4;
    const int row = tid >> 2, q = tid & 3;
    float acc[4][4] = {{0.f}};
    for (int k0 = 0; k0 < HID; k0 += 16) {
        float4 a = *(const float4*)(A + (size_t)(m0 + row) * HID + k0 + q * 4);
        float4 b = *(const float4*)(W + (size_t)(n0 + row) * HID + k0 + q * 4);
        __syncthreads();
        As[q*4+0][row] = a.x; As[q*4+1][row] = a.y; As[q*4+2][row] = a.z; As[q*4+3][row] = a.w;
        Bs[q*4+0][row] = b.x; Bs[q*4+1][row] = b.y; Bs[q*4+2][row] = b.z; Bs[q*4+3][row] = b.w;
        __syncthreads();
#pragma unroll
        for (int kk = 0; kk < 16; ++kk) {
            float av[4], bv[4];
#pragma unroll
            for (int i = 0; i < 4; ++i) { av[i] = As[kk][tm*4+i]; bv[i] = Bs[kk][tn*4+i]; }
#pragma unroll
            for (int i = 0; i < 4; ++i)
#pragma unroll
                for (int j = 0; j < 4; ++j) acc[i][j] += av[i] * bv[j];
        }
    }
#pragma unroll
    for (int i = 0; i < 4; ++i) {
        int m = m0 + tm * 4 + i;
#pragma unroll
        for (int j = 0; j < 4; ++j) {
            int n = n0 + tn * 4 + j;
            float v = acc[i][j] + bi[n] + bh[n];
            int jd = n & (HID - 1), gate = n >> 10;
            out[(size_t)m * G4 + (jd >> 3) * 32 + (jd & 7) * 4 + gate] = v;
        }
    }
}

// Detect one 512-word half (8 words/lane) with exact tag match; values land
// in v[8]. Pure global spin — no LDS side effects.
__device__ inline void detect8(const uint32* __restrict__ buf, uint32 tg,
                               int lane, uint32 v[8])
{
    for (;;) {
#pragma unroll
        for (int r = 0; r < 8; ++r)
            v[r] = __hip_atomic_load(&buf[r * 64 + lane], __ATOMIC_RELAXED, LD_AG);
        bool ok = true;
#pragma unroll
        for (int r = 0; r < 8; ++r) ok &= ((v[r] & 15u) == tg);
        if (__all(ok)) break;
    }
}

// Fused 2-layer persistent LSTM; wave-specialized, no barriers in steady state.
// Each block: waves 0-3 compute (2 h each), waves 4-7 service (poll/forward).
__global__ __launch_bounds__(NTHR)
void lstm_fused(const float* __restrict__ Whh0, const float* __restrict__ xg,
                const float* __restrict__ Wih1, const float* __restrict__ Whh1,
                const float* __restrict__ bih1, const float* __restrict__ bhh1,
                float* __restrict__ outF, Comm* __restrict__ cm)
{
    __shared__ float Wl[32 * HID];     // 131 KB: rows [localh*4+gate][1024]
    __shared__ float hlA[2][HID];
    __shared__ float hlB[2][HID];
    __shared__ int flagAlo[2], flagAhi[2], flagBlo[2], flagBhi[2];
    __shared__ int prog[4];
    __shared__ int bpA;
    const int blk = blockIdx.x, tid = threadIdx.x;
    const int wave = tid >> 6, lane = tid & 63;
    const int kb = (blk < NBLK) ? blk : blk - NBLK;
    const bool isL0 = (blk < NBLK);

    // ---- init ----
    {
        const float* Wsrc = isL0 ? Whh0 : Whh1;
#pragma unroll
        for (int i = 0; i < 16; ++i) {
            int l = i * NTHR + tid;
            int r = l >> 8, c = l & 255;
            int w = r >> 2, g = r & 3;
            ((float4*)(Wl + r * HID))[c] =
                ((const float4*)(Wsrc + (size_t)(g * HID + 8 * kb + w) * HID))[c];
        }
    }
    for (int i = tid; i < HID; i += NTHR) {
        hlA[0][i] = 0.f; hlA[1][i] = 0.f; hlB[0][i] = 0.f; hlB[1][i] = 0.f;
    }
    if (tid == 0) {
        flagAlo[0] = -2; flagAhi[0] = -2; flagAlo[1] = -1; flagAhi[1] = -1;
        flagBlo[0] = -2; flagBhi[0] = -2; flagBlo[1] = -1; flagBhi[1] = -1;
        prog[0] = prog[1] = prog[2] = prog[3] = -1;
        bpA = -1;
    }
    __syncthreads();   // the only barrier

    if (isL0) {
        const int k = kb;
        if (wave < 4) {
            // ======== layer-0 compute wave: h indices j0=8k+2w, j0+1 ========
            float c0 = 0.f, c1 = 0.f;
            float nx[8];
            if (lane == 0) {
                const float4* xp = (const float4*)(xg + k * 32 + 8 * wave);
                float4 A = xp[0], B = xp[1];
                nx[0]=A.x; nx[1]=A.y; nx[2]=A.z; nx[3]=A.w;
                nx[4]=B.x; nx[5]=B.y; nx[6]=B.z; nx[7]=B.w;
            }
            const float* wb = Wl + (size_t)(8 * wave) * HID;
            for (int t = 0; t < T_STEPS; ++t) {
                const int pm = (t - 1) & 1;
                while (__hip_atomic_load(&flagAlo[pm], __ATOMIC_ACQUIRE, LD_WG) < t - 1) {}
                while (__hip_atomic_load(&flagAhi[pm], __ATOMIC_ACQUIRE, LD_WG) < t - 1) {}
                float x[8];
#pragma unroll
                for (int i = 0; i < 8; ++i) x[i] = nx[i];
                if (lane == 0 && t + 1 < T_STEPS) {
                    const float4* xp = (const float4*)(xg + (size_t)(t + 1) * G4 + k * 32 + 8 * wave);
                    float4 A = xp[0], B = xp[1];
                    nx[0]=A.x; nx[1]=A.y; nx[2]=A.z; nx[3]=A.w;
                    nx[4]=B.x; nx[5]=B.y; nx[6]=B.z; nx[7]=B.w;
                }
                float a[8] = {0.f,0.f,0.f,0.f,0.f,0.f,0.f,0.f};
#pragma unroll 4
                for (int u = 0; u < 16; ++u) {
                    float hv = hlA[pm][u * 64 + lane];
#pragma unroll
                    for (int r = 0; r < 8; ++r)
                        a[r] += wb[r * HID + u * 64 + lane] * hv;
                }
#pragma unroll
                for (int off = 32; off > 0; off >>= 1)
#pragma unroll
                    for (int r = 0; r < 8; ++r) a[r] += __shfl_xor(a[r], off, 64);
                while (__hip_atomic_load(&bpA, __ATOMIC_RELAXED, LD_WG) < t - 8) {}
                if (lane == 0) {
                    const uint32 tg = (t >> 3) & 15;
                    float i0 = sigm(x[0] + a[0]), f0 = sigm(x[1] + a[1]);
                    float g0 = tanh_f(x[2] + a[2]), o0 = sigm(x[3] + a[3]);
                    c0 = f0 * c0 + i0 * g0;
                    float h0 = o0 * tanh_f(c0);
                    float i1 = sigm(x[4] + a[4]), f1 = sigm(x[5] + a[5]);
                    float g1 = tanh_f(x[6] + a[6]), o1 = sigm(x[7] + a[7]);
                    c1 = f1 * c1 + i1 * g1;
                    float h1 = o1 * tanh_f(c1);
                    ull pk = (ull)tagf(h0, tg) | ((ull)tagf(h1, tg) << 32);
                    __hip_atomic_store(&cm->hA[t & 7][4 * k + wave], pk,
                                       __ATOMIC_RELAXED, LD_AG);
                }
            }
        } else if (wave == 4 || wave == 5) {
            // ======== layer-0 poll wave: gather hA halves ========
            const int half = wave - 4;
            int* flg = half ? flagAhi : flagAlo;
            for (int t = 0; t <= T_STEPS - 2; ++t) {
                uint32 v[8];
                detect8((const uint32*)cm->hA[t & 7] + half * 512, (t >> 3) & 15, lane, v);
                // auto-safe: detection implies own computes passed step t
                float* dst = hlA[t & 1] + half * 512;
#pragma unroll
                for (int r = 0; r < 8; ++r) {
                    union { uint32 u; float f; } c; c.u = v[r];
                    dst[r * 64 + lane] = c.f;
                }
                if (lane == 0)
                    __hip_atomic_store(&flg[t & 1], t, __ATOMIC_RELEASE, LD_WG);
            }
        } else if (wave == 6) {
            // ======== backpressure scan: hB[s] complete -> bpA = s ========
            for (int s = 0; s <= T_STEPS - 9; ++s) {
                const uint32 tg = (s >> 3) & 15;
                const uint32* hb = (const uint32*)cm->hB[s & 7];
                for (;;) {
                    uint32 v[16]; bool ok = true;
#pragma unroll
                    for (int r = 0; r < 16; ++r)
                        v[r] = __hip_atomic_load(&hb[r * 64 + lane], __ATOMIC_RELAXED, LD_AG);
#pragma unroll
                    for (int r = 0; r < 16; ++r)
                        ok &= (((v[r] & 15u) - tg) & 15u) < 8u;   // window compare
                    if (__all(ok)) break;
                }
                if (lane == 0)
                    __hip_atomic_store(&bpA, s, __ATOMIC_RELEASE, LD_WG);
            }
        }
        // wave 7: idle, exits
    } else {
        if (wave < 4) {
            // ======== layer-1 compute wave: h indices j0=8kb+2w, j0+1 ========
            const int j0 = 8 * kb + 2 * wave;
            float wreg[128];   // [c2*4+g][u]
#pragma unroll
            for (int c2 = 0; c2 < 2; ++c2)
#pragma unroll
                for (int g = 0; g < 4; ++g)
#pragma unroll
                    for (int u = 0; u < 16; ++u)
                        wreg[(c2 * 4 + g) * 16 + u] =
                            Wih1[(size_t)(g * HID + j0 + c2) * HID + u * 64 + lane];
            float bia[8];
#pragma unroll
            for (int c2 = 0; c2 < 2; ++c2)
#pragma unroll
                for (int g = 0; g < 4; ++g)
                    bia[c2 * 4 + g] = bih1[g * HID + j0 + c2] + bhh1[g * HID + j0 + c2];
            float c0 = 0.f, c1 = 0.f;
            const float* wb = Wl + (size_t)(8 * wave) * HID;
            for (int t = 0; t < T_STEPS; ++t) {
                const int pa = t & 1, pb = (t - 1) & 1;
                while (__hip_atomic_load(&flagAlo[pa], __ATOMIC_ACQUIRE, LD_WG) < t) {}
                while (__hip_atomic_load(&flagAhi[pa], __ATOMIC_ACQUIRE, LD_WG) < t) {}
                while (__hip_atomic_load(&flagBlo[pb], __ATOMIC_ACQUIRE, LD_WG) < t - 1) {}
                while (__hip_atomic_load(&flagBhi[pb], __ATOMIC_ACQUIRE, LD_WG) < t - 1) {}
                float a[8] = {0.f,0.f,0.f,0.f,0.f,0.f,0.f,0.f};
#pragma unroll 4
                for (int u = 0; u < 16; ++u) {
                    float h0v = hlA[pa][u * 64 + lane];
                    float h1v = hlB[pb][u * 64 + lane];
#pragma unroll
                    for (int r = 0; r < 8; ++r)
                        a[r] += wb[r * HID + u * 64 + lane] * h1v + wreg[r * 16 + u] * h0v;
                }
                if (lane == 0)
                    __hip_atomic_store(&prog[wave], t, __ATOMIC_RELEASE, LD_WG);
#pragma unroll
                for (int off = 32; off > 0; off >>= 1)
#pragma unroll
                    for (int r = 0; r < 8; ++r) a[r] += __shfl_xor(a[r], off, 64);
                if (lane == 0) {
                    const uint32 tg = (t >> 3) & 15;
                    float i0 = sigm(bia[0] + a[0]), f0 = sigm(bia[1] + a[1]);
                    float g0 = tanh_f(bia[2] + a[2]), o0 = sigm(bia[3] + a[3]);
                    c0 = f0 * c0 + i0 * g0;
                    float h0 = o0 * tanh_f(c0);
                    float i1 = sigm(bia[4] + a[4]), f1 = sigm(bia[5] + a[5]);
                    float g1 = tanh_f(bia[6] + a[6]), o1 = sigm(bia[7] + a[7]);
                    c1 = f1 * c1 + i1 * g1;
                    float h1 = o1 * tanh_f(c1);
                    if (t == T_STEPS - 1) {
                        float2 o; o.x = h0; o.y = h1;
                        *(float2*)(outF + j0) = o;
                    } else {
                        ull pk = (ull)tagf(h0, tg) | ((ull)tagf(h1, tg) << 32);
                        __hip_atomic_store(&cm->hB[t & 7][4 * kb + wave], pk,
                                           __ATOMIC_RELAXED, LD_AG);
                    }
                }
            }
        } else if (wave == 4 || wave == 5) {
            // ======== layer-1 hA poll: gather h0_t halves ========
            const int half = wave - 4;
            int* flg = half ? flagAhi : flagAlo;
            for (int t = 0; t <= T_STEPS - 1; ++t) {
                uint32 v[8];
                detect8((const uint32*)cm->hA[t & 7] + half * 512, (t >> 3) & 15, lane, v);
                // guard: hlA[t&1] holds h0_{t-2}, read by computes at step t-2;
                // layer-1 may lag layer-0 by up to 7 -> must wait prog >= t-2.
                for (;;) {
                    bool ok = (lane >= 4) ||
                        (__hip_atomic_load(&prog[lane], __ATOMIC_ACQUIRE, LD_WG) >= t - 2);
                    if (__all(ok)) break;
                }
                float* dst = hlA[t & 1] + half * 512;
#pragma unroll
                for (int r = 0; r < 8; ++r) {
                    union { uint32 u; float f; } c; c.u = v[r];
                    dst[r * 64 + lane] = c.f;
                }
                if (lane == 0)
                    __hip_atomic_store(&flg[t & 1], t, __ATOMIC_RELEASE, LD_WG);
            }
        } else {
            // ======== layer-1 hB poll: gather h1_s halves (s = t-1) ========
            const int half = wave - 6;
            int* flg = half ? flagBhi : flagBlo;
            for (int s = 0; s <= T_STEPS - 2; ++s) {
                uint32 v[8];
                detect8((const uint32*)cm->hB[s & 7] + half * 512, (s >> 3) & 15, lane, v);
                // auto-safe: detection includes own computes' publishes of s
                float* dst = hlB[s & 1] + half * 512;
#pragma unroll
                for (int r = 0; r < 8; ++r) {
                    union { uint32 u; float f; } c; c.u = v[r];
                    dst[r * 64 + lane] = c.f;
                }
                if (lane == 0)
                    __hip_atomic_store(&flg[s & 1], s, __ATOMIC_RELEASE, LD_WG);
            }
        }
    }
}

extern "C" void kernel_launch(void* const* d_in, const int* in_sizes, int n_in,
                              void* d_out, int out_size, void* d_ws, size_t ws_size,
                              hipStream_t stream)
{
    const float* x    = (const float*)d_in[0];
    const float* Wih0 = (const float*)d_in[1];
    const float* Whh0 = (const float*)d_in[2];
    const float* bih0 = (const float*)d_in[3];
    const float* bhh0 = (const float*)d_in[4];
    const float* Wih1 = (const float*)d_in[5];
    const float* Whh1 = (const float*)d_in[6];
    const float* bih1 = (const float*)d_in[7];
    const float* bhh1 = (const float*)d_in[8];

    char* ws = (char*)d_ws;
    float* xg = (float*)ws;                     // 134217728 B
    Comm*  cm = (Comm*)(ws + 134217728);        // 65536 B

    (void)hipMemsetAsync(ws + 134217728, 0xFF, sizeof(Comm), stream);

    dim3 gg(G4 / 64, T_STEPS / 64);
    gemm_xg<<<gg, 256, 0, stream>>>(x, Wih0, bih0, bhh0, xg);
    lstm_fused<<<2 * NBLK, NTHR, 0, stream>>>(Whh0, xg, Wih1, Whh1, bih1, bhh1,
                                              (float*)d_out, cm);
}